// Round 3
// baseline (56.499 us; speedup 1.0000x reference)
//
#include <hip/hip_runtime.h>

#define B_  4
#define NQ_ 256
#define NK_ 512
#define H_  256

// 2*log2(e): folded into GEMM epilogue so attn's exp2 arg needs no scaling
#define C_SCALE 2.8853900817779268f

// Both small GEMMs in ONE launch. 192 blocks of 256 threads, 64x64 tiles.
// blocks [0,128): ktT[b][o][k] = C_SCALE * sum_h w1[o][h] * xk[b][k][h]
// blocks [128,192): qt[b][q][o] = C_SCALE * sum_h xq[b][q][h] * w2[o][h]
__global__ __launch_bounds__(256)
void gemm_fused(const float* __restrict__ xq, const float* __restrict__ xk,
                const float* __restrict__ w1, const float* __restrict__ w2,
                float* __restrict__ ktT, float* __restrict__ qt)
{
    constexpr int BK = 32;
    const float* A; const float* Bm; float* C;
    int ldc, m0, n0;
    {
        int id = blockIdx.x;
        if (id < 128) {                      // kt problem
            int b = id >> 5, t = id & 31;
            n0 = (t & 7) * 64; m0 = (t >> 3) * 64;
            A = w1; Bm = xk + (long)b * NK_ * H_; C = ktT + (long)b * H_ * NK_;
            ldc = NK_;
        } else {                             // qt problem
            id -= 128;
            int b = id >> 4, t = id & 15;
            n0 = (t & 3) * 64; m0 = (t >> 2) * 64;
            A = xq + (long)b * NQ_ * H_; Bm = w2; C = qt + (long)b * NQ_ * H_;
            ldc = H_;
        }
    }
    const int lda = H_, ldb = H_;

    __shared__ float As[BK][64 + 4];
    __shared__ float Bs[BK][64 + 4];

    const int tid  = threadIdx.x;
    const int lrow = tid >> 2;          // 0..63
    const int lk   = (tid & 3) * 8;     // {0,8,16,24}
    const int tm   = (tid >> 4) * 4;
    const int tn   = (tid & 15) * 4;

    float acc[4][4] = {};

    for (int kt = 0; kt < H_; kt += BK) {
        float4 a0 = *(const float4*)&A [(long)(m0 + lrow) * lda + kt + lk];
        float4 a1 = *(const float4*)&A [(long)(m0 + lrow) * lda + kt + lk + 4];
        float4 b0 = *(const float4*)&Bm[(long)(n0 + lrow) * ldb + kt + lk];
        float4 b1 = *(const float4*)&Bm[(long)(n0 + lrow) * ldb + kt + lk + 4];
        __syncthreads();
        As[lk+0][lrow]=a0.x; As[lk+1][lrow]=a0.y; As[lk+2][lrow]=a0.z; As[lk+3][lrow]=a0.w;
        As[lk+4][lrow]=a1.x; As[lk+5][lrow]=a1.y; As[lk+6][lrow]=a1.z; As[lk+7][lrow]=a1.w;
        Bs[lk+0][lrow]=b0.x; Bs[lk+1][lrow]=b0.y; Bs[lk+2][lrow]=b0.z; Bs[lk+3][lrow]=b0.w;
        Bs[lk+4][lrow]=b1.x; Bs[lk+5][lrow]=b1.y; Bs[lk+6][lrow]=b1.z; Bs[lk+7][lrow]=b1.w;
        __syncthreads();
        #pragma unroll
        for (int kk = 0; kk < BK; ++kk) {
            float4 av = *(const float4*)&As[kk][tm];
            float4 bv = *(const float4*)&Bs[kk][tn];
            float am[4] = {av.x, av.y, av.z, av.w};
            float bn[4] = {bv.x, bv.y, bv.z, bv.w};
            #pragma unroll
            for (int i = 0; i < 4; ++i)
                #pragma unroll
                for (int j = 0; j < 4; ++j)
                    acc[i][j] = fmaf(am[i], bn[j], acc[i][j]);
        }
    }
    #pragma unroll
    for (int i = 0; i < 4; ++i) {
        float4 o = {acc[i][0] * C_SCALE, acc[i][1] * C_SCALE,
                    acc[i][2] * C_SCALE, acc[i][3] * C_SCALE};
        *(float4*)&C[(long)(m0 + tm + i) * ldc + n0 + tn] = o;
    }
}

// One block per (b, q). 512 threads = one per k. Grid = 1024 blocks -> 4
// blocks/CU = 32 waves/CU (100% occupancy). Inputs pre-scaled by 2*log2e:
// prod = V - 2*sum_h v[h]*rcp(exp2(kv+qv)+1); then log_softmax over k.
__global__ __launch_bounds__(512)
void attn_main(const float* __restrict__ ktT,   // [B][H][NK], pre-scaled
               const float* __restrict__ qt,    // [B][NQ][H], pre-scaled
               const float* __restrict__ v,     // [H]
               float* __restrict__ out)         // [B][NQ][NK]
{
    const int k = threadIdx.x;           // 0..511
    const int b = blockIdx.y;
    const int q = blockIdx.x;
    const float* ktb = ktT + (long)b * H_ * NK_ + k;
    const float* qtb = qt  + ((long)b * NQ_ + q) * H_;   // wave-uniform -> s_load

    float acc = 0.f, V = 0.f;
    float ka[8], kb[8];

    // prologue: fill ka with h=0..7
    #pragma unroll
    for (int u = 0; u < 8; ++u) ka[u] = ktb[(long)u * NK_];

    for (int h0 = 0; h0 < H_; h0 += 16) {
        // prefetch h0+8..h0+15 while computing h0..h0+7
        #pragma unroll
        for (int u = 0; u < 8; ++u) kb[u] = ktb[(long)(h0 + 8 + u) * NK_];
        #pragma unroll
        for (int u = 0; u < 8; ++u) {
            float vh = v[h0 + u];                         // uniform -> s_load
            V += vh;
            float t = __builtin_amdgcn_exp2f(ka[u] + qtb[h0 + u]);
            acc = fmaf(vh, __builtin_amdgcn_rcpf(t + 1.0f), acc);
        }
        // prefetch h0+16..h0+23 (guarded, uniform branch) while computing kb
        if (h0 + 16 < H_) {
            #pragma unroll
            for (int u = 0; u < 8; ++u) ka[u] = ktb[(long)(h0 + 16 + u) * NK_];
        }
        #pragma unroll
        for (int u = 0; u < 8; ++u) {
            float vh = v[h0 + 8 + u];
            V += vh;
            float t = __builtin_amdgcn_exp2f(kb[u] + qtb[h0 + 8 + u]);
            acc = fmaf(vh, __builtin_amdgcn_rcpf(t + 1.0f), acc);
        }
    }
    float val = fmaf(-2.f, acc, V);

    // ---- log-softmax over k (512 threads = 8 waves) ----
    __shared__ float red[8];
    const int lane = k & 63, wv = k >> 6;

    float x = val;
    #pragma unroll
    for (int o = 32; o; o >>= 1) x = fmaxf(x, __shfl_xor(x, o, 64));
    if (lane == 0) red[wv] = x;
    __syncthreads();
    float m = red[0];
    #pragma unroll
    for (int w = 1; w < 8; ++w) m = fmaxf(m, red[w]);
    __syncthreads();

    float e = __builtin_amdgcn_exp2f((val - m) * 1.4426950408889634f);
    #pragma unroll
    for (int o = 32; o; o >>= 1) e += __shfl_xor(e, o, 64);
    if (lane == 0) red[wv] = e;
    __syncthreads();
    float s = 0.f;
    #pragma unroll
    for (int w = 0; w < 8; ++w) s += red[w];

    float l = __builtin_amdgcn_logf(s) * 0.6931471805599453f;  // ln(s)
    out[((long)b * NQ_ + q) * NK_ + k] = val - m - l;
}

extern "C" void kernel_launch(void* const* d_in, const int* in_sizes, int n_in,
                              void* d_out, int out_size, void* d_ws, size_t ws_size,
                              hipStream_t stream)
{
    const float* xq = (const float*)d_in[0];  // (4,256,256)
    const float* xk = (const float*)d_in[1];  // (4,512,256)
    const float* w1 = (const float*)d_in[2];  // (256,256) out,in
    const float* w2 = (const float*)d_in[3];  // (256,256)
    const float* v  = (const float*)d_in[4];  // (1,256)
    float* out = (float*)d_out;

    float* ktT = (float*)d_ws;                           // [4][256][512] = 2 MB
    float* qt  = ktT + (size_t)B_ * H_ * NK_;            // [4][256][256] = 1 MB

    gemm_fused<<<dim3(192), 256, 0, stream>>>(xq, xk, w1, w2, ktT, qt);
    attn_main<<<dim3(NQ_, B_), 512, 0, stream>>>(ktT, qt, v, out);
}

// Round 4
// 45.175 us; speedup vs baseline: 1.2507x; 1.2507x over previous
//
#include <hip/hip_runtime.h>

#define B_  4
#define NQ_ 256
#define NK_ 512
#define H_  256

// tanh(x) = 1 - 2/(exp2(x*2*log2e)+1), clamped strictly inside (-1,1) so the
// tanh-addition denominator 1+ta*tb is always > 0.
#define TWO_LOG2E 2.8853900817779268f
__device__ __forceinline__ float tanh_fast(float x) {
    float t = __builtin_amdgcn_exp2f(x * TWO_LOG2E);
    float r = __builtin_amdgcn_rcpf(t + 1.0f);
    float y = fmaf(-2.0f, r, 1.0f);
    return fminf(fmaxf(y, -0.99999994f), 0.99999994f);
}

// Both small GEMMs in ONE launch, tanh applied in the epilogue.
// blocks [0,128):  kt[b][o][k] = sum_h w1[o][h]*xk[b][k][h]
//                  -> ktTan[b][o>>2][k][o&3] = tanh(kt)       (interleaved-4)
// blocks [128,192): qt[b][q][o] = sum_h xq[b][q][h]*w2[o][h]
//                  -> tbT[b][q][o] = tanh(qt); wbT = v[o]*tanh(qt)
__global__ __launch_bounds__(256)
void gemm_fused(const float* __restrict__ xq, const float* __restrict__ xk,
                const float* __restrict__ w1, const float* __restrict__ w2,
                const float* __restrict__ v,
                float* __restrict__ ktTan,   // [B][H/4][NK][4]
                float* __restrict__ tbT,     // [B][NQ][H]
                float* __restrict__ wbT)     // [B][NQ][H]
{
    constexpr int BK = 32;
    const float* A; const float* Bm;
    int m0, n0, bz; bool iskt;
    {
        int id = blockIdx.x;
        if (id < 128) {                      // kt problem
            iskt = true;
            bz = id >> 5; int t = id & 31;
            n0 = (t & 7) * 64; m0 = (t >> 3) * 64;
            A = w1; Bm = xk + (long)bz * NK_ * H_;
        } else {                             // qt problem
            iskt = false;
            id -= 128;
            bz = id >> 4; int t = id & 15;
            n0 = (t & 3) * 64; m0 = (t >> 2) * 64;
            A = xq + (long)bz * NQ_ * H_; Bm = w2;
        }
    }
    const int lda = H_, ldb = H_;

    __shared__ float As[BK][64 + 4];
    __shared__ float Bs[BK][64 + 4];

    const int tid  = threadIdx.x;
    const int lrow = tid >> 2;          // 0..63
    const int lk   = (tid & 3) * 8;     // {0,8,16,24}
    const int tm   = (tid >> 4) * 4;
    const int tn   = (tid & 15) * 4;

    float acc[4][4] = {};

    for (int kt = 0; kt < H_; kt += BK) {
        float4 a0 = *(const float4*)&A [(long)(m0 + lrow) * lda + kt + lk];
        float4 a1 = *(const float4*)&A [(long)(m0 + lrow) * lda + kt + lk + 4];
        float4 b0 = *(const float4*)&Bm[(long)(n0 + lrow) * ldb + kt + lk];
        float4 b1 = *(const float4*)&Bm[(long)(n0 + lrow) * ldb + kt + lk + 4];
        __syncthreads();
        As[lk+0][lrow]=a0.x; As[lk+1][lrow]=a0.y; As[lk+2][lrow]=a0.z; As[lk+3][lrow]=a0.w;
        As[lk+4][lrow]=a1.x; As[lk+5][lrow]=a1.y; As[lk+6][lrow]=a1.z; As[lk+7][lrow]=a1.w;
        Bs[lk+0][lrow]=b0.x; Bs[lk+1][lrow]=b0.y; Bs[lk+2][lrow]=b0.z; Bs[lk+3][lrow]=b0.w;
        Bs[lk+4][lrow]=b1.x; Bs[lk+5][lrow]=b1.y; Bs[lk+6][lrow]=b1.z; Bs[lk+7][lrow]=b1.w;
        __syncthreads();
        #pragma unroll
        for (int kk = 0; kk < BK; ++kk) {
            float4 av = *(const float4*)&As[kk][tm];
            float4 bv = *(const float4*)&Bs[kk][tn];
            float am[4] = {av.x, av.y, av.z, av.w};
            float bn[4] = {bv.x, bv.y, bv.z, bv.w};
            #pragma unroll
            for (int i = 0; i < 4; ++i)
                #pragma unroll
                for (int j = 0; j < 4; ++j)
                    acc[i][j] = fmaf(am[i], bn[j], acc[i][j]);
        }
    }

    if (iskt) {
        // rows o = m0+tm .. +3 are consecutive -> one float4 per column j
        float* cb = ktTan + (long)bz * H_ * NK_ + (long)((m0 + tm) >> 2) * (NK_ * 4);
        #pragma unroll
        for (int j = 0; j < 4; ++j) {
            float4 t4 = { tanh_fast(acc[0][j]), tanh_fast(acc[1][j]),
                          tanh_fast(acc[2][j]), tanh_fast(acc[3][j]) };
            *(float4*)&cb[(n0 + tn + j) * 4] = t4;
        }
    } else {
        float4 v4 = *(const float4*)&v[n0 + tn];
        #pragma unroll
        for (int i = 0; i < 4; ++i) {
            float4 t4 = { tanh_fast(acc[i][0]), tanh_fast(acc[i][1]),
                          tanh_fast(acc[i][2]), tanh_fast(acc[i][3]) };
            float4 w4 = { v4.x * t4.x, v4.y * t4.y, v4.z * t4.z, v4.w * t4.w };
            long off = ((long)bz * NQ_ + m0 + tm + i) * H_ + n0 + tn;
            *(float4*)&tbT[off] = t4;
            *(float4*)&wbT[off] = w4;
        }
    }
}

// One block per (b,q), 512 threads = one per k. 1024 blocks -> 32 waves/CU.
// prod[q,k] = sum_h v[h]*(ta+tb)/(1+ta*tb)
//           = sum_h fma(v[h], ta, wb[h]) * rcp(fma(ta, tb[h], 1))
// 3 FMA + 1 rcp per element; ta via one coalesced float4 per 4 h.
__global__ __launch_bounds__(512)
void attn_main(const float4* __restrict__ kt4,  // [B][H/4][NK] float4s
               const float* __restrict__ tbT,   // [B][NQ][H]
               const float* __restrict__ wbT,   // [B][NQ][H]
               const float* __restrict__ v,     // [H]
               float* __restrict__ out)         // [B][NQ][NK]
{
    const int k = threadIdx.x, b = blockIdx.y, q = blockIdx.x;
    const float4* kp = kt4 + (long)b * (H_ / 4) * NK_ + k;
    const float* tb = tbT + ((long)b * NQ_ + q) * H_;   // wave-uniform -> s_load
    const float* wb = wbT + ((long)b * NQ_ + q) * H_;

    float acc0 = 0.f, acc1 = 0.f;
    #pragma unroll 4
    for (int hc = 0; hc < H_ / 4; ++hc) {
        float4 ta = kp[(long)hc * NK_];
        const int h = hc * 4;
        float d0 = fmaf(ta.x, tb[h+0], 1.0f);
        float p0 = fmaf(v[h+0], ta.x, wb[h+0]);
        acc0 = fmaf(p0, __builtin_amdgcn_rcpf(d0), acc0);
        float d1 = fmaf(ta.y, tb[h+1], 1.0f);
        float p1 = fmaf(v[h+1], ta.y, wb[h+1]);
        acc1 = fmaf(p1, __builtin_amdgcn_rcpf(d1), acc1);
        float d2 = fmaf(ta.z, tb[h+2], 1.0f);
        float p2 = fmaf(v[h+2], ta.z, wb[h+2]);
        acc0 = fmaf(p2, __builtin_amdgcn_rcpf(d2), acc0);
        float d3 = fmaf(ta.w, tb[h+3], 1.0f);
        float p3 = fmaf(v[h+3], ta.w, wb[h+3]);
        acc1 = fmaf(p3, __builtin_amdgcn_rcpf(d3), acc1);
    }
    float val = acc0 + acc1;

    // ---- log-softmax over k (512 threads = 8 waves) ----
    __shared__ float red[8];
    const int lane = k & 63, wv = k >> 6;

    float x = val;
    #pragma unroll
    for (int o = 32; o; o >>= 1) x = fmaxf(x, __shfl_xor(x, o, 64));
    if (lane == 0) red[wv] = x;
    __syncthreads();
    float m = red[0];
    #pragma unroll
    for (int w = 1; w < 8; ++w) m = fmaxf(m, red[w]);
    __syncthreads();

    float e = __builtin_amdgcn_exp2f((val - m) * 1.4426950408889634f);
    #pragma unroll
    for (int o = 32; o; o >>= 1) e += __shfl_xor(e, o, 64);
    if (lane == 0) red[wv] = e;
    __syncthreads();
    float s = 0.f;
    #pragma unroll
    for (int w = 0; w < 8; ++w) s += red[w];

    float l = __builtin_amdgcn_logf(s) * 0.6931471805599453f;  // ln(s)
    out[((long)b * NQ_ + q) * NK_ + k] = val - m - l;
}

extern "C" void kernel_launch(void* const* d_in, const int* in_sizes, int n_in,
                              void* d_out, int out_size, void* d_ws, size_t ws_size,
                              hipStream_t stream)
{
    const float* xq = (const float*)d_in[0];  // (4,256,256)
    const float* xk = (const float*)d_in[1];  // (4,512,256)
    const float* w1 = (const float*)d_in[2];  // (256,256) out,in
    const float* w2 = (const float*)d_in[3];  // (256,256)
    const float* v  = (const float*)d_in[4];  // (1,256)
    float* out = (float*)d_out;

    float* ktTan = (float*)d_ws;                          // [4][64][512][4] = 2 MB
    float* tbT   = ktTan + (size_t)B_ * H_ * NK_;         // [4][256][256]   = 1 MB
    float* wbT   = tbT   + (size_t)B_ * NQ_ * H_;         // [4][256][256]   = 1 MB

    gemm_fused<<<dim3(192), 256, 0, stream>>>(xq, xk, w1, w2, v, ktTan, tbT, wbT);
    attn_main<<<dim3(NQ_, B_), 512, 0, stream>>>((const float4*)ktTan, tbT, wbT, v, out);
}